// Round 5
// baseline (184.238 us; speedup 1.0000x reference)
//
#include <hip/hip_runtime.h>

#define BATCH 256
#define SEQ   2048
#define NC    32
#define EMB   2048
#define NT    64          // SEQ / BK, BK = 32

typedef unsigned short ushort_t;
using f32x2  = __attribute__((ext_vector_type(2))) float;
using f32x4  = __attribute__((ext_vector_type(4))) float;
using bf16x8 = __attribute__((ext_vector_type(8))) short;

using u32_gl = __attribute__((address_space(1))) const unsigned int;
using u32_ld = __attribute__((address_space(3))) unsigned int;

__device__ __forceinline__ unsigned int f2bf(float f) {
  unsigned int u = __float_as_uint(f);
  u += 0x7FFFu + ((u >> 16) & 1u);   // RNE (finite inputs)
  return u >> 16;
}

#define SB() __builtin_amdgcn_sched_barrier(0)

// ---------------------------------------------------------------------------
// x: (B, S, C) f32  ->  xT: (C, B, S) bf16
// ---------------------------------------------------------------------------
__global__ __launch_bounds__(256) void transpose_x_kernel(
    const float* __restrict__ x, ushort_t* __restrict__ xT) {
  __shared__ float tile[64][33];
  const int b  = blockIdx.x >> 5;
  const int st = blockIdx.x & 31;
  const int t  = threadIdx.x;
  const float* src = x + ((size_t)b * SEQ + (size_t)st * 64) * NC;
#pragma unroll
  for (int i = 0; i < 2; ++i) {
    int idx = t + i * 256;
    float4 v = reinterpret_cast<const float4*>(src)[idx];
    int s = idx >> 3;
    int c = (idx & 7) * 4;
    tile[s][c + 0] = v.x; tile[s][c + 1] = v.y;
    tile[s][c + 2] = v.z; tile[s][c + 3] = v.w;
  }
  __syncthreads();
  const int c  = t >> 3;
  const int si = (t & 7) * 8;
  unsigned int q[4];
#pragma unroll
  for (int p = 0; p < 4; ++p) {
    unsigned int h0 = f2bf(tile[si + 2 * p + 0][c]);
    unsigned int h1 = f2bf(tile[si + 2 * p + 1][c]);
    q[p] = h0 | (h1 << 16);
  }
  ushort_t* dst = xT + (size_t)c * (BATCH * SEQ) + (size_t)b * SEQ + st * 64 + si;
  *reinterpret_cast<uint4*>(dst) = make_uint4(q[0], q[1], q[2], q[3]);
}

// ---------------------------------------------------------------------------
// BM=256 / BN=128 / BK=32, 4-deep buffers, SINGLE barrier per iter, depth-2
// prefetch. 512 threads = 8 waves (4x2 of 64x64). LDS 96 KB, 1 block/CU.
// Paired-row LDS layout: row r = m>>1 (128 B), 16 B slot sig = ((h*4+g)^(r&7))
// -> 2-way (free) bank access on fragment reads; gl_lds stays linear with
// inverse-swizzled global source.
// Steady state entering iter t (in-order vmem queue):
//   [A(t):2, W(t+2):4, A(t+1):2, W(t+3):4] = 12
// body: +A(t+2):2, +W(t+4):4 -> vmcnt(12) drains A(t),W(t+2) exactly.
// ---------------------------------------------------------------------------
template <int Q>  // Q = t & 3
__device__ __forceinline__ void giter(
    int t, const ushort_t* __restrict__ xTc, const float* __restrict__ Wc,
    char* Alds, char* Blds, f32x2 (&wv)[4][4], f32x4 (&acc)[4][4],
    int tid, int wr, int wc, int g, int lm, int e0) {
  constexpr int QA = (Q + 2) & 3;   // A-stage target, W-convert set, B target

  // ---- 1. stage A(t+2): 256m x 32s bf16 = 1024 chunks, 2/thread ----
  {
    const int s0n = ((t + 2) & (NT - 1)) * 32;
#pragma unroll
    for (int i = 0; i < 2; ++i) {
      int ch = i * 512 + tid;
      int r  = ch >> 3;                 // paired row 0..127
      int sp = (ch & 7) ^ (r & 7);      // inverse swizzle -> h*4 + s8
      int m  = 2 * r + (sp >> 2);
      int s8 = sp & 3;
      const ushort_t* src = xTc + (size_t)m * SEQ + s0n + s8 * 8;
      __builtin_amdgcn_global_load_lds(
          (u32_gl*)src, (u32_ld*)(Alds + QA * 16384 + ch * 16), 16, 0, 0);
    }
  }
  SB();

  // ---- 2. issue W(t+4) -> wv[Q] (4 x f32x2, e-coalesced) ----
  {
    const int s0w = ((t + 4) & (NT - 1)) * 32;
    const float* wp = Wc + (size_t)(s0w + (tid >> 6) * 4) * EMB + e0 + (tid & 63) * 2;
#pragma unroll
    for (int j = 0; j < 4; ++j)
      wv[Q][j] = *reinterpret_cast<const f32x2*>(wp + (size_t)j * EMB);
  }
  SB();

  // ---- 3. drain A(t), W(t+2); leave 12 in flight ----
  asm volatile("s_waitcnt vmcnt(12)" ::: "memory");
  SB();

  // ---- 4. convert W(t+2) -> Blds[QA] (2 x ds_write_b64) ----
  {
    const int e2 = tid & 63;
    const int s4 = tid >> 6;            // wave id = s-group
#pragma unroll
    for (int d = 0; d < 2; ++d) {
      const int e = e2 * 2 + d;
      unsigned int lo = f2bf(wv[QA][0][d]) | (f2bf(wv[QA][1][d]) << 16);
      unsigned int hi = f2bf(wv[QA][2][d]) | (f2bf(wv[QA][3][d]) << 16);
      int sig  = (((e & 1) << 2) + (s4 >> 1)) ^ ((e >> 1) & 7);
      int byte = (e >> 1) * 128 + sig * 16 + (s4 & 1) * 8;
      *reinterpret_cast<uint2*>(Blds + QA * 8192 + byte) = make_uint2(lo, hi);
    }
  }
  asm volatile("s_waitcnt lgkmcnt(0)" ::: "memory");
  SB();

  // ---- 5. single barrier ----
  __builtin_amdgcn_s_barrier();

  // ---- 6. compute(t) from Alds[Q], Blds[Q] ----
  {
    bf16x8 af[4], bfr[4];
#pragma unroll
    for (int mi = 0; mi < 4; ++mi) {
      int m  = wr * 64 + mi * 16 + lm;
      int r  = m >> 1;
      int sig = (((m & 1) << 2) + g) ^ (r & 7);
      af[mi] = *reinterpret_cast<const bf16x8*>(Alds + Q * 16384 + r * 128 + sig * 16);
    }
#pragma unroll
    for (int ni = 0; ni < 4; ++ni) {
      int e  = wc * 64 + ni * 16 + lm;
      int r  = e >> 1;
      int sig = (((e & 1) << 2) + g) ^ (r & 7);
      bfr[ni] = *reinterpret_cast<const bf16x8*>(Blds + Q * 8192 + r * 128 + sig * 16);
    }
#pragma unroll
    for (int mi = 0; mi < 4; ++mi)
#pragma unroll
      for (int ni = 0; ni < 4; ++ni)
        acc[mi][ni] = __builtin_amdgcn_mfma_f32_16x16x32_bf16(
            af[mi], bfr[ni], acc[mi][ni], 0, 0, 0);
  }
}

__global__ __launch_bounds__(512, 1) void grouped_gemm_pipe(
    const ushort_t* __restrict__ xT,  // (C,B,S) bf16
    const float* __restrict__ W,      // (C,S,E) f32
    const float* __restrict__ bias,   // (C,E) f32
    float* __restrict__ out) {        // (B,C,E) f32
  __shared__ ushort_t AldsU[4][256 * 32];  // 64 KB
  __shared__ ushort_t BldsU[4][128 * 32];  // 32 KB -> 96 KB total

  // Bijective XCD-chunked swizzle: nwg = 512; all 16 e-tiles of a channel on
  // one XCD (A tile L2-resident there).
  const int bid = (blockIdx.x & 7) * 64 + (blockIdx.x >> 3);
  const int c   = bid >> 4;
  const int et  = bid & 15;
  const int e0  = et * 128;

  const int tid  = threadIdx.x;
  const int w    = tid >> 6;
  const int wr   = w >> 1;           // 0..3 m-quadrant
  const int wc   = w & 1;            // 0..1 e-half
  const int lane = tid & 63;
  const int g    = lane >> 4;        // k-group (s-run g*8, BK=32)
  const int lm   = lane & 15;

  const float* Wc = W + (size_t)c * SEQ * EMB;
  const ushort_t* xTc = xT + (size_t)c * (BATCH * SEQ);
  char* Alds = (char*)&AldsU[0][0];
  char* Blds = (char*)&BldsU[0][0];

  f32x2 wv[4][4];
  f32x4 acc[4][4];
#pragma unroll
  for (int i = 0; i < 4; ++i)
#pragma unroll
    for (int j = 0; j < 4; ++j) acc[i][j] = (f32x4){0.f, 0.f, 0.f, 0.f};

  // ---- prologue: queue order W0,W1,A0,W2,A1,W3 (20 outstanding) ----
  {
    const int s4 = tid >> 6;
    const int e2 = tid & 63;
    const float* wpb = Wc + (size_t)(s4 * 4) * EMB + e0 + e2 * 2;
#pragma unroll
    for (int j = 0; j < 4; ++j)
      wv[0][j] = *reinterpret_cast<const f32x2*>(wpb + (size_t)j * EMB);
    SB();
#pragma unroll
    for (int j = 0; j < 4; ++j)
      wv[1][j] = *reinterpret_cast<const f32x2*>(wpb + (size_t)(32 + j) * EMB);
    SB();
#pragma unroll
    for (int i = 0; i < 2; ++i) {      // A(0)
      int ch = i * 512 + tid;
      int r  = ch >> 3;
      int sp = (ch & 7) ^ (r & 7);
      int m  = 2 * r + (sp >> 2);
      const ushort_t* src = xTc + (size_t)m * SEQ + (sp & 3) * 8;
      __builtin_amdgcn_global_load_lds(
          (u32_gl*)src, (u32_ld*)(Alds + ch * 16), 16, 0, 0);
    }
    SB();
#pragma unroll
    for (int j = 0; j < 4; ++j)
      wv[2][j] = *reinterpret_cast<const f32x2*>(wpb + (size_t)(64 + j) * EMB);
    SB();
#pragma unroll
    for (int i = 0; i < 2; ++i) {      // A(1)
      int ch = i * 512 + tid;
      int r  = ch >> 3;
      int sp = (ch & 7) ^ (r & 7);
      int m  = 2 * r + (sp >> 2);
      const ushort_t* src = xTc + (size_t)m * SEQ + 32 + (sp & 3) * 8;
      __builtin_amdgcn_global_load_lds(
          (u32_gl*)src, (u32_ld*)(Alds + 16384 + ch * 16), 16, 0, 0);
    }
    SB();
#pragma unroll
    for (int j = 0; j < 4; ++j)
      wv[3][j] = *reinterpret_cast<const f32x2*>(wpb + (size_t)(96 + j) * EMB);
    SB();

    // convert W(0) -> Blds[0], W(1) -> Blds[1]
    asm volatile("s_waitcnt vmcnt(16)" ::: "memory");
    SB();
#pragma unroll
    for (int d = 0; d < 2; ++d) {
      const int e = e2 * 2 + d;
      unsigned int lo = f2bf(wv[0][0][d]) | (f2bf(wv[0][1][d]) << 16);
      unsigned int hi = f2bf(wv[0][2][d]) | (f2bf(wv[0][3][d]) << 16);
      int sig  = (((e & 1) << 2) + (s4 >> 1)) ^ ((e >> 1) & 7);
      int byte = (e >> 1) * 128 + sig * 16 + (s4 & 1) * 8;
      *reinterpret_cast<uint2*>(Blds + byte) = make_uint2(lo, hi);
    }
    SB();
    asm volatile("s_waitcnt vmcnt(12)" ::: "memory");
    SB();
#pragma unroll
    for (int d = 0; d < 2; ++d) {
      const int e = e2 * 2 + d;
      unsigned int lo = f2bf(wv[1][0][d]) | (f2bf(wv[1][1][d]) << 16);
      unsigned int hi = f2bf(wv[1][2][d]) | (f2bf(wv[1][3][d]) << 16);
      int sig  = (((e & 1) << 2) + (s4 >> 1)) ^ ((e >> 1) & 7);
      int byte = (e >> 1) * 128 + sig * 16 + (s4 & 1) * 8;
      *reinterpret_cast<uint2*>(Blds + 8192 + byte) = make_uint2(lo, hi);
    }
    SB();
  }

  // ---- main loop: 64 iters, unroll-4, wrapped prefetch ----
  for (int t = 0; t < NT; t += 4) {
    giter<0>(t,     xTc, Wc, Alds, Blds, wv, acc, tid, wr, wc, g, lm, e0);
    giter<1>(t + 1, xTc, Wc, Alds, Blds, wv, acc, tid, wr, wc, g, lm, e0);
    giter<2>(t + 2, xTc, Wc, Alds, Blds, wv, acc, tid, wr, wc, g, lm, e0);
    giter<3>(t + 3, xTc, Wc, Alds, Blds, wv, acc, tid, wr, wc, g, lm, e0);
  }

  // drain wrapped prefetch junk
  asm volatile("s_waitcnt vmcnt(0)" ::: "memory");

  // ---- epilogue: bias + ReLU; D: col=lane&15, row=(lane>>4)*4+reg ----
  const float* bc = bias + (size_t)c * EMB;
#pragma unroll
  for (int ni = 0; ni < 4; ++ni) {
    const int e = e0 + wc * 64 + ni * 16 + lm;
    const float bv = bc[e];
#pragma unroll
    for (int mi = 0; mi < 4; ++mi) {
      f32x4 a = acc[mi][ni];
      const int mbase = wr * 64 + mi * 16 + g * 4;
#pragma unroll
      for (int r = 0; r < 4; ++r) {
        float v = a[r] + bv;
        v = fmaxf(v, 0.f);
        out[((size_t)(mbase + r) * NC + c) * EMB + e] = v;
      }
    }
  }
}

// ---------------------------------------------------------------------------
// Fallback (no workspace): round-1 style, A loaded strided from x directly.
// ---------------------------------------------------------------------------
__global__ __launch_bounds__(256, 2) void grouped_gemm_fallback(
    const float* __restrict__ x, const float* __restrict__ W,
    const float* __restrict__ bias, float* __restrict__ out) {
  __shared__ ushort_t Alds[128 * 64];
  __shared__ ushort_t Blds[128 * 64];
  const int bid = blockIdx.x;
  const int c   = bid >> 5;
  const int et  = (bid >> 1) & 15;
  const int bt  = bid & 1;
  const int b0  = bt * 128;
  const int e0  = et * 128;
  const int tid  = threadIdx.x;
  const int w    = tid >> 6;
  const int wr   = w >> 1;
  const int wc   = w & 1;
  const int lane = tid & 63;
  const int g    = lane >> 4;
  const int lm   = lane & 15;
  const float* Wc = W + (size_t)c * SEQ * EMB;
  const int srow8 = tid >> 5;
  const int e4    = tid & 31;
  f32x4 acc[4][4];
#pragma unroll
  for (int i = 0; i < 4; ++i)
#pragma unroll
    for (int j = 0; j < 4; ++j) acc[i][j] = (f32x4){0.f, 0.f, 0.f, 0.f};
  for (int s0 = 0; s0 < SEQ; s0 += 64) {
#pragma unroll
    for (int i = 0; i < 4; ++i) {
      int ch   = i * 256 + tid;
      int m    = ch >> 3;
      int slot = (ch & 7) ^ (m & 7);
      const float* src = x + (size_t)(b0 + m) * (SEQ * NC)
                           + (size_t)(s0 + slot * 8) * NC + c;
      unsigned int q[4];
#pragma unroll
      for (int p = 0; p < 4; ++p) {
        unsigned int h0 = f2bf(src[(2 * p + 0) * NC]);
        unsigned int h1 = f2bf(src[(2 * p + 1) * NC]);
        q[p] = h0 | (h1 << 16);
      }
      *reinterpret_cast<uint4*>((char*)&Alds[0] + ch * 16) =
          make_uint4(q[0], q[1], q[2], q[3]);
    }
    {
      const float* wp = Wc + (size_t)(s0 + srow8 * 8) * EMB + e0 + e4 * 4;
      f32x4 wvv[8];
#pragma unroll
      for (int r = 0; r < 8; ++r)
        wvv[r] = *reinterpret_cast<const f32x4*>(wp + (size_t)r * EMB);
#pragma unroll
      for (int i = 0; i < 4; ++i) {
        const int e_local = e4 * 4 + i;
        unsigned int q0 = f2bf(wvv[0][i]) | (f2bf(wvv[1][i]) << 16);
        unsigned int q1 = f2bf(wvv[2][i]) | (f2bf(wvv[3][i]) << 16);
        unsigned int q2 = f2bf(wvv[4][i]) | (f2bf(wvv[5][i]) << 16);
        unsigned int q3 = f2bf(wvv[6][i]) | (f2bf(wvv[7][i]) << 16);
        int byte = (e_local * 128 + srow8 * 16) ^ ((e_local & 7) << 4);
        *reinterpret_cast<uint4*>((char*)&Blds[0] + byte) =
            make_uint4(q0, q1, q2, q3);
      }
    }
    __syncthreads();
#pragma unroll
    for (int ks = 0; ks < 2; ++ks) {
      bf16x8 af[4], bfr[4];
#pragma unroll
      for (int mi = 0; mi < 4; ++mi) {
        int m_local = wr * 64 + mi * 16 + lm;
        int byte = (m_local * 128 + (ks * 4 + g) * 16) ^ ((m_local & 7) << 4);
        af[mi] = *reinterpret_cast<const bf16x8*>((const char*)&Alds[0] + byte);
      }
#pragma unroll
      for (int ni = 0; ni < 4; ++ni) {
        int e_local = wc * 64 + ni * 16 + lm;
        int byte = (e_local * 128 + (ks * 4 + g) * 16) ^ ((e_local & 7) << 4);
        bfr[ni] = *reinterpret_cast<const bf16x8*>((const char*)&Blds[0] + byte);
      }
#pragma unroll
      for (int mi = 0; mi < 4; ++mi)
#pragma unroll
        for (int ni = 0; ni < 4; ++ni)
          acc[mi][ni] = __builtin_amdgcn_mfma_f32_16x16x32_bf16(
              af[mi], bfr[ni], acc[mi][ni], 0, 0, 0);
    }
    __syncthreads();
  }
  const float* bc = bias + (size_t)c * EMB;
#pragma unroll
  for (int ni = 0; ni < 4; ++ni) {
    const int e = e0 + wc * 64 + ni * 16 + lm;
    const float bv = bc[e];
#pragma unroll
    for (int mi = 0; mi < 4; ++mi) {
      f32x4 a = acc[mi][ni];
      const int mbase = b0 + wr * 64 + mi * 16 + g * 4;
#pragma unroll
      for (int r = 0; r < 4; ++r) {
        float v = a[r] + bv;
        v = fmaxf(v, 0.f);
        out[((size_t)(mbase + r) * NC + c) * EMB + e] = v;
      }
    }
  }
}

extern "C" void kernel_launch(void* const* d_in, const int* in_sizes, int n_in,
                              void* d_out, int out_size, void* d_ws, size_t ws_size,
                              hipStream_t stream) {
  const float* x    = (const float*)d_in[0];
  const float* W    = (const float*)d_in[1];
  const float* bias = (const float*)d_in[2];
  float* out        = (float*)d_out;

  const size_t xT_bytes = (size_t)NC * BATCH * SEQ * sizeof(ushort_t);

  if (ws_size >= xT_bytes) {
    ushort_t* xT = (ushort_t*)d_ws;
    transpose_x_kernel<<<BATCH * (SEQ / 64), 256, 0, stream>>>(x, xT);
    grouped_gemm_pipe<<<NC * (EMB / 128), 512, 0, stream>>>(xT, W, bias, out);
  } else {
    grouped_gemm_fallback<<<NC * 2 * (EMB / 128), 256, 0, stream>>>(x, W, bias, out);
  }
}